// Round 13
// baseline (281.789 us; speedup 1.0000x reference)
//
#include <hip/hip_runtime.h>
#include <hip/hip_fp16.h>
#include <cstdint>
#include <cstddef>

// Problem constants (from reference): N=100000, F_IN=64, F1=128, F2=64,
// E=3200000, NUM_GRAPHS=1024. N and E derived from in_sizes at launch.
// R24 = R23 + conv1-agg/MLP fusion (16-wave blocks: 16 aggs -> LDS tile ->
// 4-wave MFMA MLP; deletes agg1h round-trip and hides MLP under agg latency).
// Agg core at confirmed latency floor (R14/R17/R22/R23). R19/R20 lessons:
// bucketed staging is load-bearing; keep same per-wave agg concurrency.
#define NGRAPH 1024
#define CHUNK 8192       // edges per block in scatter pass (391 blocks @ E=3.2M)
#define SCTHREADS 512
#define SCIT (CHUNK / SCTHREADS)   // 16 edges per thread
#define MAXB 512         // max buckets (supports N <= 131072; here B=391)
#define CAP 16384        // padded bucket capacity (~12.3K used @ min-48 pad)
#define WIDE 2048        // wide-grid block count for streaming kernels

typedef _Float16 f16x8 __attribute__((ext_vector_type(8)));
typedef float f32x4 __attribute__((ext_vector_type(4)));
typedef float f32x2 __attribute__((ext_vector_type(2)));

// ================= one-pass padded-bucket CSR build =================
// bucket b = dst >> 8. Edge word packs (dst & 255) << 24 | src (src < 2^24).
// Bucket b owns ebuck/esrc slots [b*CAP, b*CAP + bcnt[b]).
// Block-local LDS counting sort -> coalesced global writes (full-line runs).

__global__ __launch_bounds__(SCTHREADS) void scatter1_kernel(const int* __restrict__ src,
        const int* __restrict__ dst, int E, int B,
        int* __restrict__ bcnt, unsigned* __restrict__ ebuck) {
    __shared__ unsigned sorted[CHUNK];      // 32 KB
    __shared__ int h[MAXB];                 // histogram
    __shared__ int lo[MAXB];                // exclusive local offsets
    __shared__ int cur[MAXB];               // LDS scatter cursors
    __shared__ int gbase[MAXB];             // reserved global base per bucket
    __shared__ int wsum[8];                 // wave sums for shuffle scan
    int blk = blockIdx.x, tid = threadIdx.x;
    int base = blk * CHUNK;
    int cnt_i = E - base; if (cnt_i > CHUNK) cnt_i = CHUNK;

    h[tid] = 0;
    __syncthreads();

    // load edges to registers + LDS histogram
    unsigned rd[SCIT], rs[SCIT];
    #pragma unroll
    for (int it = 0; it < SCIT; ++it) {
        int i = base + tid + it * SCTHREADS;
        if (i < E) {
            rd[it] = (unsigned)dst[i];
            rs[it] = (unsigned)src[i];
            atomicAdd(&h[rd[it] >> 8], 1);
        } else rd[it] = 0xFFFFFFFFu;
    }
    __syncthreads();

    // reserve global range for this block's share of each bucket
    int hv = h[tid];
    if (tid < B) gbase[tid] = hv ? atomicAdd(&bcnt[tid], hv) : 0;

    // two-level shuffle scan (inclusive) of h over 512 entries.
    int lane = tid & 63, wv = tid >> 6;
    int val = hv;
    #pragma unroll
    for (int o = 1; o < 64; o <<= 1) {
        int t = __shfl_up(val, o, 64);
        if (lane >= o) val += t;
    }
    if (lane == 63) wsum[wv] = val;
    __syncthreads();
    if (tid == 0) {
        int run = 0;
        #pragma unroll
        for (int i = 0; i < 8; ++i) { int t = wsum[i]; wsum[i] = run; run += t; }
    }
    __syncthreads();
    int excl = wsum[wv] + val - hv;
    lo[tid] = excl;
    cur[tid] = excl;
    __syncthreads();

    // scatter into LDS in bucket-sorted order
    #pragma unroll
    for (int it = 0; it < SCIT; ++it) {
        if (rd[it] != 0xFFFFFFFFu) {
            int b = rd[it] >> 8;
            int p = atomicAdd(&cur[b], 1);
            sorted[p] = ((rd[it] & 255u) << 24) | rs[it];
        }
    }
    __syncthreads();

    // coalesced copy-out: consecutive j -> consecutive global slots per bucket
    // run. Bucket lookup via proportional hint + local walk.
    for (int j = tid; j < cnt_i; j += SCTHREADS) {
        int l = (int)(((long long)j * B) / cnt_i);
        if (l > B - 1) l = B - 1;
        while (lo[l] > j) --l;
        while (l + 1 < B && lo[l + 1] <= j) ++l;
        ebuck[(size_t)l * CAP + gbase[l] + (j - lo[l])] = sorted[j];
    }
}

// Pass 2: one block per bucket. LDS histogram -> deg/dinv/row_beg/row_end,
// LDS-cursor scatter of src into esrc. Rows padded to multiple-of-16, min 48,
// sentinel src=N (zero row) -> uniform U=6 agg. Shuffle scan + 4-deep unroll.
__global__ __launch_bounds__(256) void fine_kernel(const unsigned* __restrict__ ebuck,
        const int* __restrict__ bcnt, int N, int B,
        int* __restrict__ row_beg, int* __restrict__ row_end, float* __restrict__ dinv,
        int* __restrict__ esrc) {
    __shared__ int hcnt[256];
    __shared__ int loff[256];
    __shared__ int wsum[4];
    int b = blockIdx.x, tid = threadIdx.x;
    int beg = b * CAP;
    int cnt = bcnt[b];
    hcnt[tid] = 0;
    __syncthreads();
    {
        int e = tid;
        for (; e + 768 < cnt; e += 1024) {
            unsigned u0 = ebuck[beg + e];
            unsigned u1 = ebuck[beg + e + 256];
            unsigned u2 = ebuck[beg + e + 512];
            unsigned u3 = ebuck[beg + e + 768];
            atomicAdd(&hcnt[u0 >> 24], 1);
            atomicAdd(&hcnt[u1 >> 24], 1);
            atomicAdd(&hcnt[u2 >> 24], 1);
            atomicAdd(&hcnt[u3 >> 24], 1);
        }
        for (; e < cnt; e += 256)
            atomicAdd(&hcnt[ebuck[beg + e] >> 24], 1);
    }
    __syncthreads();
    int v = hcnt[tid];
    int n = (b << 8) + tid;
    int vp = (v + 15) & ~15;           // padded row length (multiple of 16)
    if (vp < 48) vp = 48;              // min-48: uniform U=6 in agg kernels
    if (n >= N) vp = 0;                // ghost nodes (last bucket): no slots

    // shuffle scan (inclusive) of vp over 256 entries (4 waves)
    int lane = tid & 63, wv = tid >> 6;
    int val = vp;
    #pragma unroll
    for (int o = 1; o < 64; o <<= 1) {
        int t = __shfl_up(val, o, 64);
        if (lane >= o) val += t;
    }
    if (lane == 63) wsum[wv] = val;
    __syncthreads();
    if (tid == 0) {
        int run = 0;
        #pragma unroll
        for (int i = 0; i < 4; ++i) { int t = wsum[i]; wsum[i] = run; run += t; }
    }
    __syncthreads();
    int excl = wsum[wv] + val - vp;

    float d = rsqrtf((float)(v + 1));   // +1 self loop
    if (n < N) {
        row_beg[n] = beg + excl;
        row_end[n] = beg + excl + vp;   // padded end
        dinv[n] = d;
    }
    loff[tid] = excl;
    __syncthreads();
    {
        int e = tid;
        for (; e + 768 < cnt; e += 1024) {
            unsigned u0 = ebuck[beg + e];
            unsigned u1 = ebuck[beg + e + 256];
            unsigned u2 = ebuck[beg + e + 512];
            unsigned u3 = ebuck[beg + e + 768];
            int p0 = atomicAdd(&loff[u0 >> 24], 1);
            esrc[beg + p0] = (int)(u0 & 0xFFFFFF);
            int p1 = atomicAdd(&loff[u1 >> 24], 1);
            esrc[beg + p1] = (int)(u1 & 0xFFFFFF);
            int p2 = atomicAdd(&loff[u2 >> 24], 1);
            esrc[beg + p2] = (int)(u2 & 0xFFFFFF);
            int p3 = atomicAdd(&loff[u3 >> 24], 1);
            esrc[beg + p3] = (int)(u3 & 0xFFFFFF);
        }
        for (; e < cnt; e += 256) {
            unsigned u = ebuck[beg + e];
            int p = atomicAdd(&loff[u >> 24], 1);
            esrc[beg + p] = (int)(u & 0xFFFFFF);
        }
    }
    // sentinel pad: src = N (zero row in xs/ts)
    for (int p = excl + v; p < excl + vp; ++p) esrc[beg + p] = N;
}

// xs_q[n][f] = fp8(x[n][f]*dinv[n]) — pure streaming, wide grid.
__global__ __launch_bounds__(256) void pack_kernel(const float* __restrict__ x,
        const float* __restrict__ dinv, int N, unsigned char* __restrict__ xs) {
    int j = blockIdx.x * 256 + threadIdx.x;
    int total = N * 16;
    int stride = gridDim.x * 256;
    const float4* xr = (const float4*)x;
    for (; j < total; j += stride) {
        int node = j >> 4, cc = j & 15;
        float dd = dinv[node];
        float4 vv = xr[(size_t)node * 16 + cc];
        int lo2 = __builtin_amdgcn_cvt_pk_fp8_f32(vv.x * dd, vv.y * dd, 0, false);
        int hi2 = __builtin_amdgcn_cvt_pk_fp8_f32(vv.z * dd, vv.w * dd, 0, false);
        ((unsigned*)xs)[(size_t)node * 16 + cc] =
            (unsigned)(lo2 & 0xffff) | ((unsigned)(hi2 & 0xffff) << 16);
    }
}

// ======== prep: block 0 = weight swizzle + sentinel-row zeros + zero-bias;
//          blocks 1+ = goff binary search + bcnt 0
// W1s slot s = ((ks*8+nt)*4+q)*16+n  -> 8 halfs W1[ks*32+q*8+j][nt*16+n]
// W2s slot s = ((ks2*4+n2)*4+q)*16+n -> 8 halfs W2[ks2*32+q*8+j][n2*16+n]
__global__ __launch_bounds__(256) void prep_kernel(const float* __restrict__ W1,
        const float* __restrict__ W2, __half* __restrict__ W1s, __half* __restrict__ W2s,
        const int* __restrict__ batch, int N, int* __restrict__ goff,
        int* __restrict__ bcnt, unsigned char* __restrict__ xsq,
        unsigned char* __restrict__ tsq, float* __restrict__ zbias) {
    int t = threadIdx.x;
    if (blockIdx.x == 0) {
        #pragma unroll
        for (int it = 0; it < 4; ++it) {
            int s = t + it * 256;
            int n = s & 15, q = (s >> 4) & 3, nt = (s >> 6) & 7, ks = s >> 9;
            int k0 = ks * 32 + q * 8, col = nt * 16 + n;
            __align__(16) __half h[8];
            #pragma unroll
            for (int j = 0; j < 8; ++j) h[j] = (__half)W1[(k0 + j) * 128 + col];
            *((uint4*)&W1s[(size_t)s * 8]) = *(uint4*)h;
        }
        #pragma unroll
        for (int it = 0; it < 4; ++it) {
            int s = t + it * 256;
            int n = s & 15, q = (s >> 4) & 3, n2 = (s >> 6) & 3, ks2 = s >> 8;
            int k0 = ks2 * 32 + q * 8, col = n2 * 16 + n;
            __align__(16) __half h[8];
            #pragma unroll
            for (int j = 0; j < 8; ++j) h[j] = (__half)W2[(k0 + j) * 64 + col];
            *((uint4*)&W2s[(size_t)s * 8]) = *(uint4*)h;
        }
        uint4 z; z.x = 0; z.y = 0; z.z = 0; z.w = 0;
        if (t < 4)    // zero sentinel row xsq[N] (64 fp8 = 4 uint4)
            ((uint4*)(xsq + (size_t)N * 64))[t] = z;
        if (t < 4)    // zero sentinel row tsq[N]
            ((uint4*)(tsq + (size_t)N * 64))[t] = z;
        if (t < 64) zbias[t] = 0.f;   // conv2... (kept; unused by fused conv1)
    } else {
        int g = (blockIdx.x - 1) * 256 + t;
        if (g < MAXB) bcnt[g] = 0;
        if (g > NGRAPH) return;
        if (g == NGRAPH) { goff[g] = N; return; }
        int lo = 0, hi = N;
        while (lo < hi) {
            int mid = (lo + hi) >> 1;
            if (batch[mid] < g) lo = mid + 1; else hi = mid;
        }
        goff[g] = lo;
    }
}

// ---------------- aggregation core (fp8 gather, HW decode, f32 accum) --------
// 64-lane wave per node: 8 groups x 8 lanes. Group g owns CONTIGUOUS slots
// [beg + g*U, beg + (g+1)*U) (U = vp/8, even) -> int2 index loads.
// R14/R17/R22/R23 confirmed: sits at the random-gather latency floor (~47us).
__device__ __forceinline__ void acc8q(f32x2* a, const uint2& u) {
    a[0] += __builtin_amdgcn_cvt_pk_f32_fp8(u.x, false);
    a[1] += __builtin_amdgcn_cvt_pk_f32_fp8(u.x, true);
    a[2] += __builtin_amdgcn_cvt_pk_f32_fp8(u.y, false);
    a[3] += __builtin_amdgcn_cvt_pk_f32_fp8(u.y, true);
}

__device__ __forceinline__ void agg_core_q(const uint2* __restrict__ ts2,
        const int* __restrict__ esrc, int beg, int endp, int n, int g, int c,
        float* a) {
    f32x2 h0[4] = {}, h1[4] = {};
    if (g == 0) acc8q(h0, ts2[(size_t)n * 8 + c]);   // self loop
    int U = (endp - beg) >> 3;   // per-group edges, even, wave-uniform
    int e0 = beg + g * U;        // group-major contiguous (int2-aligned: U even)
    if (U == 6) {
        int2 p0 = *(const int2*)&esrc[e0];
        int2 p1 = *(const int2*)&esrc[e0 + 2];
        int2 p2 = *(const int2*)&esrc[e0 + 4];
        uint2 u0 = ts2[(size_t)p0.x * 8 + c];
        uint2 u1 = ts2[(size_t)p0.y * 8 + c];
        uint2 u2 = ts2[(size_t)p1.x * 8 + c];
        uint2 u3 = ts2[(size_t)p1.y * 8 + c];
        uint2 u4 = ts2[(size_t)p2.x * 8 + c];
        uint2 u5 = ts2[(size_t)p2.y * 8 + c];
        acc8q(h0, u0); acc8q(h1, u1); acc8q(h0, u2); acc8q(h1, u3);
        acc8q(h0, u4); acc8q(h1, u5);
    } else if (U > 0) {
        // rare high-degree path (U even, >= 8): int2-paired, 2-chain
        for (int j = 0; j < U; j += 2) {
            int2 p = *(const int2*)&esrc[e0 + j];
            uint2 ua = ts2[(size_t)p.x * 8 + c];
            uint2 ub = ts2[(size_t)p.y * 8 + c];
            acc8q(h0, ua);
            acc8q(h1, ub);
        }
    }
    #pragma unroll
    for (int i = 0; i < 4; ++i) {
        a[2 * i]     = h0[i].x + h1[i].x;
        a[2 * i + 1] = h0[i].y + h1[i].y;
    }
}

// R24: fused conv1-agg + MLP. 16 waves: wave w aggs node base+w (same
// per-wave structure/concurrency as agg_q2h) -> fp16 row in LDS; then
// waves 0-3 run the 16-node MFMA MLP (GEMM1 split by nt, GEMM2 by n2)
// and store fp8 ts_q. Deletes agg1h round-trip; MLP pipelines under
// other blocks' gather latency. launch_bounds(1024,8): VGPR<=64 so the
// agg phase keeps 32 waves/CU.
__global__ __launch_bounds__(1024, 8) void agg1mlp_kernel(
        const unsigned char* __restrict__ ts, const int* __restrict__ esrc,
        const int* __restrict__ row_beg, const int* __restrict__ row_end,
        const float* __restrict__ dinv, const __half* __restrict__ W1s,
        const __half* __restrict__ W2s, const float* __restrict__ b1,
        unsigned char* __restrict__ T, int N) {
    __shared__ __align__(16) __half ldsA[16][72];   // stride 144B: 2-way-conflict reads
    __shared__ __align__(16) __half h1t[16][136];
    int tid = threadIdx.x;
    int w = tid >> 6, lane = tid & 63;
    int base = blockIdx.x * 16;
    int n = base + w;
    int g = lane >> 3, c = lane & 7;

    if (n < N) {
        const uint2* ts2 = (const uint2*)ts;
        float a[8];
        agg_core_q(ts2, esrc, row_beg[n], row_end[n], n, g, c, a);
        #pragma unroll
        for (int i = 0; i < 8; ++i) {
            a[i] += __shfl_xor(a[i], 8, 64);
            a[i] += __shfl_xor(a[i], 16, 64);
            a[i] += __shfl_xor(a[i], 32, 64);
        }
        if (g == 0) {
            float d = dinv[n];
            __align__(16) __half2 h[4];
            #pragma unroll
            for (int i = 0; i < 4; ++i)
                h[i] = __floats2half2_rn(a[2 * i] * d, a[2 * i + 1] * d);
            ((uint4*)&ldsA[w][0])[c] = *(uint4*)h;
        }
    } else if (g == 0) {
        uint4 z; z.x = 0; z.y = 0; z.z = 0; z.w = 0;
        ((uint4*)&ldsA[w][0])[c] = z;
    }
    __syncthreads();

    int n15 = lane & 15, q = lane >> 4;
    if (w < 4) {
        // GEMM1: h1 = relu(A @ W1 + b1); wave w owns nt = {2w, 2w+1}
        uint4 ua0 = ((const uint4*)&ldsA[n15][0])[q];
        uint4 ua1 = ((const uint4*)&ldsA[n15][0])[4 + q];
        f16x8 a10 = *(f16x8*)&ua0;
        f16x8 a11 = *(f16x8*)&ua1;
        const uint4* W1f = (const uint4*)W1s;
        #pragma unroll
        for (int j = 0; j < 2; ++j) {
            int nt = w * 2 + j;
            f32x4 cc = {0.f, 0.f, 0.f, 0.f};
            uint4 ub0 = W1f[(nt * 4 + q) * 16 + n15];           // ks=0
            uint4 ub1 = W1f[((8 + nt) * 4 + q) * 16 + n15];     // ks=1
            cc = __builtin_amdgcn_mfma_f32_16x16x32_f16(a10, *(f16x8*)&ub0, cc, 0, 0, 0);
            cc = __builtin_amdgcn_mfma_f32_16x16x32_f16(a11, *(f16x8*)&ub1, cc, 0, 0, 0);
            float bv = b1[nt * 16 + n15];
            #pragma unroll
            for (int rr = 0; rr < 4; ++rr) {
                float hv = fmaxf(cc[rr] + bv, 0.f);
                h1t[q * 4 + rr][nt * 16 + n15] = (__half)hv;    // row=node, col=feat
            }
        }
    }
    __syncthreads();
    if (w >= 4) return;

    // GEMM2: ts = (h1 @ W2) * dinv, fp8 store; wave w owns n2 = w
    f16x8 a2[4];
    #pragma unroll
    for (int ks2 = 0; ks2 < 4; ++ks2)
        a2[ks2] = *(f16x8*)&h1t[n15][ks2 * 32 + q * 8];
    const uint4* W2f = (const uint4*)W2s;
    f32x4 cc = {0.f, 0.f, 0.f, 0.f};
    #pragma unroll
    for (int ks2 = 0; ks2 < 4; ++ks2) {
        uint4 ub = W2f[((ks2 * 4 + w) * 4 + q) * 16 + n15];
        cc = __builtin_amdgcn_mfma_f32_16x16x32_f16(a2[ks2], *(f16x8*)&ub, cc, 0, 0, 0);
    }
    #pragma unroll
    for (int rr = 0; rr < 4; ++rr) {
        int node = base + q * 4 + rr;
        if (node < N) {
            float v = cc[rr] * dinv[node];
            int pk = __builtin_amdgcn_cvt_pk_fp8_f32(v, v, 0, false);
            T[(size_t)node * 64 + w * 16 + n15] = (unsigned char)(pk & 0xff);
        }
    }
}

// conv2 aggregate: fp8 gather (HW decode) + bias, fp16 output (feeds readout).
__global__ __launch_bounds__(256) void agg_q2h_kernel(const unsigned char* __restrict__ ts,
        const int* __restrict__ esrc, const int* __restrict__ row_beg,
        const int* __restrict__ row_end, const float* __restrict__ dinv,
        const float* __restrict__ bias, __half* __restrict__ out, int N) {
    int n = blockIdx.x * 4 + (threadIdx.x >> 6);
    if (n >= N) return;
    int lane = threadIdx.x & 63;
    int g = lane >> 3, c = lane & 7;
    const uint2* ts2 = (const uint2*)ts;     // row stride 8 uint2 (64 fp8)
    float a[8];
    agg_core_q(ts2, esrc, row_beg[n], row_end[n], n, g, c, a);
    #pragma unroll
    for (int i = 0; i < 8; ++i) {
        a[i] += __shfl_xor(a[i], 8, 64);
        a[i] += __shfl_xor(a[i], 16, 64);
        a[i] += __shfl_xor(a[i], 32, 64);
    }
    if (g == 0) {
        float d = dinv[n];
        float4 bb0 = ((const float4*)bias)[c * 2];
        float4 bb1 = ((const float4*)bias)[c * 2 + 1];
        __align__(16) __half2 h[4];
        h[0] = __floats2half2_rn(a[0] * d + bb0.x, a[1] * d + bb0.y);
        h[1] = __floats2half2_rn(a[2] * d + bb0.z, a[3] * d + bb0.w);
        h[2] = __floats2half2_rn(a[4] * d + bb1.x, a[5] * d + bb1.y);
        h[3] = __floats2half2_rn(a[6] * d + bb1.z, a[7] * d + bb1.w);
        ((uint4*)out)[(size_t)n * 8 + c] = *(uint4*)h;
    }
}

// ---------------- fused readout + head: out[g] = [mean|max](h2 rows) @ Wm + bm
// h2 is fp16 (halves the readout's streaming read).
__global__ __launch_bounds__(256) void readout_head_kernel(const __half* __restrict__ h2,
        const int* __restrict__ goff, const float* __restrict__ Wm,
        const float* __restrict__ bm, float* __restrict__ out) {
    int g = blockIdx.x;
    int beg = goff[g], end = goff[g + 1];
    int f = threadIdx.x & 63;
    int c = threadIdx.x >> 6;
    float s = 0.f, m = -3.4e38f;
    for (int n = beg + c; n < end; n += 4) {
        float v = __half2float(h2[(size_t)n * 64 + f]);
        s += v;
        m = fmaxf(m, v);
    }
    __shared__ float ss[4][64], sm[4][64];
    __shared__ float rr[128];
    ss[c][f] = s; sm[c][f] = m;
    __syncthreads();
    if (c == 0) {
        float S = ss[0][f] + ss[1][f] + ss[2][f] + ss[3][f];
        float M = fmaxf(fmaxf(sm[0][f], sm[1][f]), fmaxf(sm[2][f], sm[3][f]));
        int cnt = end - beg;
        rr[f] = (cnt > 0) ? S / (float)cnt : 0.f;
        rr[64 + f] = (cnt > 0) ? M : 0.f;
    }
    __syncthreads();
    if (threadIdx.x < 64) {
        int j = threadIdx.x;
        float acc = bm[j];
        #pragma unroll 4
        for (int k = 0; k < 128; ++k)
            acc = fmaf(rr[k], Wm[k * 64 + j], acc);
        out[(size_t)g * 64 + j] = acc;
    }
}

extern "C" void kernel_launch(void* const* d_in, const int* in_sizes, int n_in,
                              void* d_out, int out_size, void* d_ws, size_t ws_size,
                              hipStream_t stream) {
    const float* x    = (const float*)d_in[0];
    const int*  adj   = (const int*)d_in[1];
    const int*  batch = (const int*)d_in[2];
    const float* W1   = (const float*)d_in[3];
    const float* b1   = (const float*)d_in[4];
    const float* W2   = (const float*)d_in[5];
    const float* b2   = (const float*)d_in[6];
    const float* Wm   = (const float*)d_in[7];
    const float* bm   = (const float*)d_in[8];
    float* out = (float*)d_out;

    const int N = in_sizes[0] / 64;
    const int E = in_sizes[1] / 2;
    const int* src = adj;
    const int* dst = adj + E;
    const int B = (N + 255) >> 8;                 // buckets (391)
    const int nblocks = (E + CHUNK - 1) / CHUNK;  // scatter blocks (391)

    // ---- workspace carve (256B aligned) ----
    char* w = (char*)d_ws;
    size_t off = 0;
    auto carve = [&](size_t bytes) -> void* {
        void* p = w + off;
        off += (bytes + 255) & ~(size_t)255;
        return p;
    };
    size_t halfbuf = (size_t)N * 64 * 2;
    float* dinv    = (float*)carve((size_t)N * 4);
    int*   row_beg = (int*)  carve((size_t)N * 4);
    int*   row_end = (int*)  carve((size_t)N * 4);
    int*   esrc    = (int*)  carve((size_t)B * CAP * 4);
    unsigned* ebuck= (unsigned*)carve((size_t)B * CAP * 4);
    int*   bcnt    = (int*)  carve((MAXB + 1) * 4);
    int*   goff    = (int*)  carve((NGRAPH + 1) * 4);
    __half* W1s    = (__half*)carve(8192 * 2);
    __half* W2s    = (__half*)carve(8192 * 2);
    unsigned char* xs_q = (unsigned char*)carve((size_t)N * 64 + 64);  // fp8 + sentinel
    __half* h2     = (__half*)carve(halfbuf);
    unsigned char* ts_q = (unsigned char*)carve((size_t)N * 64 + 64);  // fp8 + sentinel
    float* zbias   = (float*)carve(256);

    // prep: W swizzle + sentinel zeros + zbias (block 0); bcnt=0 + goff (blocks 1+)
    prep_kernel<<<1 + (NGRAPH + 256) / 256, 256, 0, stream>>>(W1, W2, W1s, W2s,
                                                              batch, N, goff, bcnt,
                                                              xs_q, ts_q, zbias);

    // CSR build (bucketed structure — write-amplification-safe)
    scatter1_kernel<<<nblocks, SCTHREADS, 0, stream>>>(src, dst, E, B, bcnt, ebuck);
    fine_kernel<<<B, 256, 0, stream>>>(ebuck, bcnt, N, B, row_beg, row_end,
                                       dinv, esrc);

    // xs pack at full TLP
    pack_kernel<<<WIDE, 256, 0, stream>>>(x, dinv, N, xs_q);

    // fused conv1 aggregate + MLP: ts_q = fp8((relu((dinv*(S+I)xs)@W1+b1)@W2)*dinv)
    agg1mlp_kernel<<<(N + 15) / 16, 1024, 0, stream>>>(xs_q, esrc, row_beg, row_end,
                                                       dinv, W1s, W2s, b1, ts_q, N);

    // conv2 aggregate: h2 = half(dinv*(S+I)ts_q + b2)  [fp8 HW gather]
    agg_q2h_kernel<<<(N + 3) / 4, 256, 0, stream>>>(ts_q, esrc, row_beg, row_end,
                                                    dinv, b2, h2, N);

    // fused readout + head
    readout_head_kernel<<<NGRAPH, 256, 0, stream>>>(h2, goff, Wm, bm, out);
}

// Round 14
// 270.531 us; speedup vs baseline: 1.0416x; 1.0416x over previous
//
#include <hip/hip_runtime.h>
#include <hip/hip_fp16.h>
#include <cstdint>
#include <cstddef>

// Problem constants (from reference): N=100000, F_IN=64, F1=128, F2=64,
// E=3200000, NUM_GRAPHS=1024. N and E derived from in_sizes at launch.
// R25 = revert to R23 (measured best 272.8us). R24's agg+MLP fusion FAILED
// (75us vs 47+15: block barrier gates on slowest-of-16 agg tails + 4/16-wave
// MLP phase holds slots idle). Agg latency floor now QUADRUPLE-confirmed
// (R14 depth / R17 bytes / R22 issue-rate / R24 fusion). R19/R20: bucketed
// staging is load-bearing (direct scatter = 15x write amplification).
#define NGRAPH 1024
#define CHUNK 8192       // edges per block in scatter pass (391 blocks @ E=3.2M)
#define SCTHREADS 512
#define SCIT (CHUNK / SCTHREADS)   // 16 edges per thread
#define MAXB 512         // max buckets (supports N <= 131072; here B=391)
#define CAP 16384        // padded bucket capacity (~12.3K used @ min-48 pad)
#define WIDE 2048        // wide-grid block count for streaming kernels

typedef _Float16 f16x8 __attribute__((ext_vector_type(8)));
typedef float f32x4 __attribute__((ext_vector_type(4)));
typedef float f32x2 __attribute__((ext_vector_type(2)));

// ================= one-pass padded-bucket CSR build =================
// bucket b = dst >> 8. Edge word packs (dst & 255) << 24 | src (src < 2^24).
// Bucket b owns ebuck/esrc slots [b*CAP, b*CAP + bcnt[b]).
// Block-local LDS counting sort -> coalesced global writes (full-line runs).

__global__ __launch_bounds__(SCTHREADS) void scatter1_kernel(const int* __restrict__ src,
        const int* __restrict__ dst, int E, int B,
        int* __restrict__ bcnt, unsigned* __restrict__ ebuck) {
    __shared__ unsigned sorted[CHUNK];      // 32 KB
    __shared__ int h[MAXB];                 // histogram
    __shared__ int lo[MAXB];                // exclusive local offsets
    __shared__ int cur[MAXB];               // LDS scatter cursors
    __shared__ int gbase[MAXB];             // reserved global base per bucket
    __shared__ int wsum[8];                 // wave sums for shuffle scan
    int blk = blockIdx.x, tid = threadIdx.x;
    int base = blk * CHUNK;
    int cnt_i = E - base; if (cnt_i > CHUNK) cnt_i = CHUNK;

    h[tid] = 0;
    __syncthreads();

    // load edges to registers + LDS histogram
    unsigned rd[SCIT], rs[SCIT];
    #pragma unroll
    for (int it = 0; it < SCIT; ++it) {
        int i = base + tid + it * SCTHREADS;
        if (i < E) {
            rd[it] = (unsigned)dst[i];
            rs[it] = (unsigned)src[i];
            atomicAdd(&h[rd[it] >> 8], 1);
        } else rd[it] = 0xFFFFFFFFu;
    }
    __syncthreads();

    // reserve global range for this block's share of each bucket
    int hv = h[tid];
    if (tid < B) gbase[tid] = hv ? atomicAdd(&bcnt[tid], hv) : 0;

    // two-level shuffle scan (inclusive) of h over 512 entries.
    int lane = tid & 63, wv = tid >> 6;
    int val = hv;
    #pragma unroll
    for (int o = 1; o < 64; o <<= 1) {
        int t = __shfl_up(val, o, 64);
        if (lane >= o) val += t;
    }
    if (lane == 63) wsum[wv] = val;
    __syncthreads();
    if (tid == 0) {
        int run = 0;
        #pragma unroll
        for (int i = 0; i < 8; ++i) { int t = wsum[i]; wsum[i] = run; run += t; }
    }
    __syncthreads();
    int excl = wsum[wv] + val - hv;
    lo[tid] = excl;
    cur[tid] = excl;
    __syncthreads();

    // scatter into LDS in bucket-sorted order
    #pragma unroll
    for (int it = 0; it < SCIT; ++it) {
        if (rd[it] != 0xFFFFFFFFu) {
            int b = rd[it] >> 8;
            int p = atomicAdd(&cur[b], 1);
            sorted[p] = ((rd[it] & 255u) << 24) | rs[it];
        }
    }
    __syncthreads();

    // coalesced copy-out: consecutive j -> consecutive global slots per bucket
    // run. Bucket lookup via proportional hint + local walk.
    for (int j = tid; j < cnt_i; j += SCTHREADS) {
        int l = (int)(((long long)j * B) / cnt_i);
        if (l > B - 1) l = B - 1;
        while (lo[l] > j) --l;
        while (l + 1 < B && lo[l + 1] <= j) ++l;
        ebuck[(size_t)l * CAP + gbase[l] + (j - lo[l])] = sorted[j];
    }
}

// Pass 2: one block per bucket. LDS histogram -> deg/dinv/row_beg/row_end,
// LDS-cursor scatter of src into esrc. Rows padded to multiple-of-16, min 48,
// sentinel src=N (zero row) -> uniform U=6 agg. Shuffle scan + 4-deep unroll.
__global__ __launch_bounds__(256) void fine_kernel(const unsigned* __restrict__ ebuck,
        const int* __restrict__ bcnt, int N, int B,
        int* __restrict__ row_beg, int* __restrict__ row_end, float* __restrict__ dinv,
        int* __restrict__ esrc) {
    __shared__ int hcnt[256];
    __shared__ int loff[256];
    __shared__ int wsum[4];
    int b = blockIdx.x, tid = threadIdx.x;
    int beg = b * CAP;
    int cnt = bcnt[b];
    hcnt[tid] = 0;
    __syncthreads();
    {
        int e = tid;
        for (; e + 768 < cnt; e += 1024) {
            unsigned u0 = ebuck[beg + e];
            unsigned u1 = ebuck[beg + e + 256];
            unsigned u2 = ebuck[beg + e + 512];
            unsigned u3 = ebuck[beg + e + 768];
            atomicAdd(&hcnt[u0 >> 24], 1);
            atomicAdd(&hcnt[u1 >> 24], 1);
            atomicAdd(&hcnt[u2 >> 24], 1);
            atomicAdd(&hcnt[u3 >> 24], 1);
        }
        for (; e < cnt; e += 256)
            atomicAdd(&hcnt[ebuck[beg + e] >> 24], 1);
    }
    __syncthreads();
    int v = hcnt[tid];
    int n = (b << 8) + tid;
    int vp = (v + 15) & ~15;           // padded row length (multiple of 16)
    if (vp < 48) vp = 48;              // min-48: uniform U=6 in agg kernels
    if (n >= N) vp = 0;                // ghost nodes (last bucket): no slots

    // shuffle scan (inclusive) of vp over 256 entries (4 waves)
    int lane = tid & 63, wv = tid >> 6;
    int val = vp;
    #pragma unroll
    for (int o = 1; o < 64; o <<= 1) {
        int t = __shfl_up(val, o, 64);
        if (lane >= o) val += t;
    }
    if (lane == 63) wsum[wv] = val;
    __syncthreads();
    if (tid == 0) {
        int run = 0;
        #pragma unroll
        for (int i = 0; i < 4; ++i) { int t = wsum[i]; wsum[i] = run; run += t; }
    }
    __syncthreads();
    int excl = wsum[wv] + val - vp;

    float d = rsqrtf((float)(v + 1));   // +1 self loop
    if (n < N) {
        row_beg[n] = beg + excl;
        row_end[n] = beg + excl + vp;   // padded end
        dinv[n] = d;
    }
    loff[tid] = excl;
    __syncthreads();
    {
        int e = tid;
        for (; e + 768 < cnt; e += 1024) {
            unsigned u0 = ebuck[beg + e];
            unsigned u1 = ebuck[beg + e + 256];
            unsigned u2 = ebuck[beg + e + 512];
            unsigned u3 = ebuck[beg + e + 768];
            int p0 = atomicAdd(&loff[u0 >> 24], 1);
            esrc[beg + p0] = (int)(u0 & 0xFFFFFF);
            int p1 = atomicAdd(&loff[u1 >> 24], 1);
            esrc[beg + p1] = (int)(u1 & 0xFFFFFF);
            int p2 = atomicAdd(&loff[u2 >> 24], 1);
            esrc[beg + p2] = (int)(u2 & 0xFFFFFF);
            int p3 = atomicAdd(&loff[u3 >> 24], 1);
            esrc[beg + p3] = (int)(u3 & 0xFFFFFF);
        }
        for (; e < cnt; e += 256) {
            unsigned u = ebuck[beg + e];
            int p = atomicAdd(&loff[u >> 24], 1);
            esrc[beg + p] = (int)(u & 0xFFFFFF);
        }
    }
    // sentinel pad: src = N (zero row in xs/ts)
    for (int p = excl + v; p < excl + vp; ++p) esrc[beg + p] = N;
}

// xs_q[n][f] = fp8(x[n][f]*dinv[n]) — pure streaming, wide grid.
__global__ __launch_bounds__(256) void pack_kernel(const float* __restrict__ x,
        const float* __restrict__ dinv, int N, unsigned char* __restrict__ xs) {
    int j = blockIdx.x * 256 + threadIdx.x;
    int total = N * 16;
    int stride = gridDim.x * 256;
    const float4* xr = (const float4*)x;
    for (; j < total; j += stride) {
        int node = j >> 4, cc = j & 15;
        float dd = dinv[node];
        float4 vv = xr[(size_t)node * 16 + cc];
        int lo2 = __builtin_amdgcn_cvt_pk_fp8_f32(vv.x * dd, vv.y * dd, 0, false);
        int hi2 = __builtin_amdgcn_cvt_pk_fp8_f32(vv.z * dd, vv.w * dd, 0, false);
        ((unsigned*)xs)[(size_t)node * 16 + cc] =
            (unsigned)(lo2 & 0xffff) | ((unsigned)(hi2 & 0xffff) << 16);
    }
}

// ======== prep: block 0 = weight swizzle + sentinel-row zeros + zero-bias;
//          blocks 1+ = goff binary search + bcnt 0
// W1s slot s = ((ks*8+nt)*4+q)*16+n  -> 8 halfs W1[ks*32+q*8+j][nt*16+n]
// W2s slot s = ((ks2*4+n2)*4+q)*16+n -> 8 halfs W2[ks2*32+q*8+j][n2*16+n]
__global__ __launch_bounds__(256) void prep_kernel(const float* __restrict__ W1,
        const float* __restrict__ W2, __half* __restrict__ W1s, __half* __restrict__ W2s,
        const int* __restrict__ batch, int N, int* __restrict__ goff,
        int* __restrict__ bcnt, unsigned char* __restrict__ xsq,
        unsigned char* __restrict__ tsq, float* __restrict__ zbias) {
    int t = threadIdx.x;
    if (blockIdx.x == 0) {
        #pragma unroll
        for (int it = 0; it < 4; ++it) {
            int s = t + it * 256;
            int n = s & 15, q = (s >> 4) & 3, nt = (s >> 6) & 7, ks = s >> 9;
            int k0 = ks * 32 + q * 8, col = nt * 16 + n;
            __align__(16) __half h[8];
            #pragma unroll
            for (int j = 0; j < 8; ++j) h[j] = (__half)W1[(k0 + j) * 128 + col];
            *((uint4*)&W1s[(size_t)s * 8]) = *(uint4*)h;
        }
        #pragma unroll
        for (int it = 0; it < 4; ++it) {
            int s = t + it * 256;
            int n = s & 15, q = (s >> 4) & 3, n2 = (s >> 6) & 3, ks2 = s >> 8;
            int k0 = ks2 * 32 + q * 8, col = n2 * 16 + n;
            __align__(16) __half h[8];
            #pragma unroll
            for (int j = 0; j < 8; ++j) h[j] = (__half)W2[(k0 + j) * 64 + col];
            *((uint4*)&W2s[(size_t)s * 8]) = *(uint4*)h;
        }
        uint4 z; z.x = 0; z.y = 0; z.z = 0; z.w = 0;
        if (t < 4)    // zero sentinel row xsq[N] (64 fp8 = 4 uint4)
            ((uint4*)(xsq + (size_t)N * 64))[t] = z;
        if (t < 4)    // zero sentinel row tsq[N]
            ((uint4*)(tsq + (size_t)N * 64))[t] = z;
        if (t < 64) zbias[t] = 0.f;   // conv1 zero bias (f32 +0 is exact)
    } else {
        int g = (blockIdx.x - 1) * 256 + t;
        if (g < MAXB) bcnt[g] = 0;
        if (g > NGRAPH) return;
        if (g == NGRAPH) { goff[g] = N; return; }
        int lo = 0, hi = N;
        while (lo < hi) {
            int mid = (lo + hi) >> 1;
            if (batch[mid] < g) lo = mid + 1; else hi = mid;
        }
        goff[g] = lo;
    }
}

// ---------------- aggregation core (fp8 gather, HW decode, f32 accum) --------
// 64-lane wave per node: 8 groups x 8 lanes. Group g owns CONTIGUOUS slots
// [beg + g*U, beg + (g+1)*U) (U = vp/8, even) -> int2 index loads.
// Gathers all issue before any accumulate wait (6 in flight).
// R14/R17/R22/R24 confirmed: sits at the random-gather latency floor (~47us).
__device__ __forceinline__ void acc8q(f32x2* a, const uint2& u) {
    a[0] += __builtin_amdgcn_cvt_pk_f32_fp8(u.x, false);
    a[1] += __builtin_amdgcn_cvt_pk_f32_fp8(u.x, true);
    a[2] += __builtin_amdgcn_cvt_pk_f32_fp8(u.y, false);
    a[3] += __builtin_amdgcn_cvt_pk_f32_fp8(u.y, true);
}

__device__ __forceinline__ void agg_core_q(const uint2* __restrict__ ts2,
        const int* __restrict__ esrc, int beg, int endp, int n, int g, int c,
        float* a) {
    f32x2 h0[4] = {}, h1[4] = {};
    if (g == 0) acc8q(h0, ts2[(size_t)n * 8 + c]);   // self loop
    int U = (endp - beg) >> 3;   // per-group edges, even, wave-uniform
    int e0 = beg + g * U;        // group-major contiguous (int2-aligned: U even)
    if (U == 6) {
        int2 p0 = *(const int2*)&esrc[e0];
        int2 p1 = *(const int2*)&esrc[e0 + 2];
        int2 p2 = *(const int2*)&esrc[e0 + 4];
        uint2 u0 = ts2[(size_t)p0.x * 8 + c];
        uint2 u1 = ts2[(size_t)p0.y * 8 + c];
        uint2 u2 = ts2[(size_t)p1.x * 8 + c];
        uint2 u3 = ts2[(size_t)p1.y * 8 + c];
        uint2 u4 = ts2[(size_t)p2.x * 8 + c];
        uint2 u5 = ts2[(size_t)p2.y * 8 + c];
        acc8q(h0, u0); acc8q(h1, u1); acc8q(h0, u2); acc8q(h1, u3);
        acc8q(h0, u4); acc8q(h1, u5);
    } else if (U > 0) {
        // rare high-degree path (U even, >= 8): int2-paired, 2-chain
        for (int j = 0; j < U; j += 2) {
            int2 p = *(const int2*)&esrc[e0 + j];
            uint2 ua = ts2[(size_t)p.x * 8 + c];
            uint2 ub = ts2[(size_t)p.y * 8 + c];
            acc8q(h0, ua);
            acc8q(h1, ub);
        }
    }
    #pragma unroll
    for (int i = 0; i < 4; ++i) {
        a[2 * i]     = h0[i].x + h1[i].x;
        a[2 * i + 1] = h0[i].y + h1[i].y;
    }
}

// aggregate: fp8 gather (HW decode) + bias, fp16 output.
// Used for BOTH convs (conv1 passes a zeroed bias; f32 +0 is exact).
__global__ __launch_bounds__(256) void agg_q2h_kernel(const unsigned char* __restrict__ ts,
        const int* __restrict__ esrc, const int* __restrict__ row_beg,
        const int* __restrict__ row_end, const float* __restrict__ dinv,
        const float* __restrict__ bias, __half* __restrict__ out, int N) {
    int n = blockIdx.x * 4 + (threadIdx.x >> 6);
    if (n >= N) return;
    int lane = threadIdx.x & 63;
    int g = lane >> 3, c = lane & 7;
    const uint2* ts2 = (const uint2*)ts;     // row stride 8 uint2 (64 fp8)
    float a[8];
    agg_core_q(ts2, esrc, row_beg[n], row_end[n], n, g, c, a);
    #pragma unroll
    for (int i = 0; i < 8; ++i) {
        a[i] += __shfl_xor(a[i], 8, 64);
        a[i] += __shfl_xor(a[i], 16, 64);
        a[i] += __shfl_xor(a[i], 32, 64);
    }
    if (g == 0) {
        float d = dinv[n];
        float4 bb0 = ((const float4*)bias)[c * 2];
        float4 bb1 = ((const float4*)bias)[c * 2 + 1];
        __align__(16) __half2 h[4];
        h[0] = __floats2half2_rn(a[0] * d + bb0.x, a[1] * d + bb0.y);
        h[1] = __floats2half2_rn(a[2] * d + bb0.z, a[3] * d + bb0.w);
        h[2] = __floats2half2_rn(a[4] * d + bb1.x, a[5] * d + bb1.y);
        h[3] = __floats2half2_rn(a[6] * d + bb1.z, a[7] * d + bb1.w);
        ((uint4*)out)[(size_t)n * 8 + c] = *(uint4*)h;
    }
}

// ---------------- fused MLP (MFMA fp16): ts = (relu(A@W1+b1) @ W2) * dinv ----
// fp8 store via HW v_cvt_pk_fp8_f32.
__global__ __launch_bounds__(256) void fusedmlp_kernel(const __half* __restrict__ A,
        const __half* __restrict__ W1s, const __half* __restrict__ W2s,
        const float* __restrict__ b1, const float* __restrict__ dinv,
        unsigned char* __restrict__ T, int N) {
    __shared__ __align__(16) __half h1t[4][16][136];   // per-wave 16x128 tile, padded rows
    int tid = threadIdx.x;
    int w = tid >> 6, lane = tid & 63;
    int n15 = lane & 15, q = lane >> 4;
    int base = blockIdx.x * 64 + w * 16;

    int m = base + n15; if (m >= N) m = N - 1;          // clamp; stores guarded
    const uint4* Ar = (const uint4*)(A + (size_t)m * 64);
    uint4 ua0 = Ar[q];
    uint4 ua1 = Ar[4 + q];
    f16x8 a10 = *(f16x8*)&ua0;
    f16x8 a11 = *(f16x8*)&ua1;
    const uint4* W1f = (const uint4*)W1s;
    #pragma unroll
    for (int nt = 0; nt < 8; ++nt) {
        f32x4 c = {0.f, 0.f, 0.f, 0.f};
        uint4 ub0 = W1f[(nt * 4 + q) * 16 + n15];           // ks=0
        uint4 ub1 = W1f[((8 + nt) * 4 + q) * 16 + n15];     // ks=1
        c = __builtin_amdgcn_mfma_f32_16x16x32_f16(a10, *(f16x8*)&ub0, c, 0, 0, 0);
        c = __builtin_amdgcn_mfma_f32_16x16x32_f16(a11, *(f16x8*)&ub1, c, 0, 0, 0);
        float bv = b1[nt * 16 + n15];
        #pragma unroll
        for (int rr = 0; rr < 4; ++rr) {
            float hv = fmaxf(c[rr] + bv, 0.f);
            h1t[w][q * 4 + rr][nt * 16 + n15] = (__half)hv;  // row=node, col=feat
        }
    }
    __syncthreads();

    f16x8 a2[4];
    #pragma unroll
    for (int ks2 = 0; ks2 < 4; ++ks2)
        a2[ks2] = *(f16x8*)&h1t[w][n15][ks2 * 32 + q * 8];
    const uint4* W2f = (const uint4*)W2s;
    #pragma unroll
    for (int n2 = 0; n2 < 4; ++n2) {
        f32x4 c = {0.f, 0.f, 0.f, 0.f};
        #pragma unroll
        for (int ks2 = 0; ks2 < 4; ++ks2) {
            uint4 ub = W2f[((ks2 * 4 + n2) * 4 + q) * 16 + n15];
            c = __builtin_amdgcn_mfma_f32_16x16x32_f16(a2[ks2], *(f16x8*)&ub, c, 0, 0, 0);
        }
        #pragma unroll
        for (int rr = 0; rr < 4; ++rr) {
            int node = base + q * 4 + rr;
            if (node < N) {
                float v = c[rr] * dinv[node];
                int pk = __builtin_amdgcn_cvt_pk_fp8_f32(v, v, 0, false);
                T[(size_t)node * 64 + n2 * 16 + n15] = (unsigned char)(pk & 0xff);
            }
        }
    }
}

// ---------------- fused readout + head: out[g] = [mean|max](h2 rows) @ Wm + bm
// h2 is fp16 (halves the readout's streaming read).
__global__ __launch_bounds__(256) void readout_head_kernel(const __half* __restrict__ h2,
        const int* __restrict__ goff, const float* __restrict__ Wm,
        const float* __restrict__ bm, float* __restrict__ out) {
    int g = blockIdx.x;
    int beg = goff[g], end = goff[g + 1];
    int f = threadIdx.x & 63;
    int c = threadIdx.x >> 6;
    float s = 0.f, m = -3.4e38f;
    for (int n = beg + c; n < end; n += 4) {
        float v = __half2float(h2[(size_t)n * 64 + f]);
        s += v;
        m = fmaxf(m, v);
    }
    __shared__ float ss[4][64], sm[4][64];
    __shared__ float rr[128];
    ss[c][f] = s; sm[c][f] = m;
    __syncthreads();
    if (c == 0) {
        float S = ss[0][f] + ss[1][f] + ss[2][f] + ss[3][f];
        float M = fmaxf(fmaxf(sm[0][f], sm[1][f]), fmaxf(sm[2][f], sm[3][f]));
        int cnt = end - beg;
        rr[f] = (cnt > 0) ? S / (float)cnt : 0.f;
        rr[64 + f] = (cnt > 0) ? M : 0.f;
    }
    __syncthreads();
    if (threadIdx.x < 64) {
        int j = threadIdx.x;
        float acc = bm[j];
        #pragma unroll 4
        for (int k = 0; k < 128; ++k)
            acc = fmaf(rr[k], Wm[k * 64 + j], acc);
        out[(size_t)g * 64 + j] = acc;
    }
}

extern "C" void kernel_launch(void* const* d_in, const int* in_sizes, int n_in,
                              void* d_out, int out_size, void* d_ws, size_t ws_size,
                              hipStream_t stream) {
    const float* x    = (const float*)d_in[0];
    const int*  adj   = (const int*)d_in[1];
    const int*  batch = (const int*)d_in[2];
    const float* W1   = (const float*)d_in[3];
    const float* b1   = (const float*)d_in[4];
    const float* W2   = (const float*)d_in[5];
    const float* b2   = (const float*)d_in[6];
    const float* Wm   = (const float*)d_in[7];
    const float* bm   = (const float*)d_in[8];
    float* out = (float*)d_out;

    const int N = in_sizes[0] / 64;
    const int E = in_sizes[1] / 2;
    const int* src = adj;
    const int* dst = adj + E;
    const int B = (N + 255) >> 8;                 // buckets (391)
    const int nblocks = (E + CHUNK - 1) / CHUNK;  // scatter blocks (391)

    // ---- workspace carve (256B aligned) ----
    char* w = (char*)d_ws;
    size_t off = 0;
    auto carve = [&](size_t bytes) -> void* {
        void* p = w + off;
        off += (bytes + 255) & ~(size_t)255;
        return p;
    };
    size_t halfbuf = (size_t)N * 64 * 2;
    float* dinv    = (float*)carve((size_t)N * 4);
    int*   row_beg = (int*)  carve((size_t)N * 4);
    int*   row_end = (int*)  carve((size_t)N * 4);
    int*   esrc    = (int*)  carve((size_t)B * CAP * 4);
    unsigned* ebuck= (unsigned*)carve((size_t)B * CAP * 4);
    int*   bcnt    = (int*)  carve((MAXB + 1) * 4);
    int*   goff    = (int*)  carve((NGRAPH + 1) * 4);
    __half* W1s    = (__half*)carve(8192 * 2);
    __half* W2s    = (__half*)carve(8192 * 2);
    unsigned char* xs_q = (unsigned char*)carve((size_t)N * 64 + 64);  // fp8 + sentinel
    __half* agg1h  = (__half*)carve(halfbuf);
    __half* h2     = (__half*)carve(halfbuf);
    unsigned char* ts_q = (unsigned char*)carve((size_t)N * 64 + 64);  // fp8 + sentinel
    float* zbias   = (float*)carve(256);

    // prep: W swizzle + sentinel zeros + zbias (block 0); bcnt=0 + goff (blocks 1+)
    prep_kernel<<<1 + (NGRAPH + 256) / 256, 256, 0, stream>>>(W1, W2, W1s, W2s,
                                                              batch, N, goff, bcnt,
                                                              xs_q, ts_q, zbias);

    // CSR build (bucketed structure — write-amplification-safe)
    scatter1_kernel<<<nblocks, SCTHREADS, 0, stream>>>(src, dst, E, B, bcnt, ebuck);
    fine_kernel<<<B, 256, 0, stream>>>(ebuck, bcnt, N, B, row_beg, row_end,
                                       dinv, esrc);

    // xs pack at full TLP
    pack_kernel<<<WIDE, 256, 0, stream>>>(x, dinv, N, xs_q);

    // conv1 aggregate: agg1h = half(dinv*(S+I)xs_q)   [fp8 HW gather, zero bias]
    agg_q2h_kernel<<<(N + 3) / 4, 256, 0, stream>>>(xs_q, esrc, row_beg, row_end,
                                                    dinv, zbias, agg1h, N);

    // fused MLP: ts_q = fp8((relu(agg1h@W1 + b1) @ W2) * dinv)  [HW cvt]
    fusedmlp_kernel<<<(N + 63) / 64, 256, 0, stream>>>(agg1h, W1s, W2s, b1, dinv, ts_q, N);

    // conv2 aggregate: h2 = half(dinv*(S+I)ts_q + b2)  [fp8 HW gather]
    agg_q2h_kernel<<<(N + 3) / 4, 256, 0, stream>>>(ts_q, esrc, row_beg, row_end,
                                                    dinv, b2, h2, N);

    // fused readout + head
    readout_head_kernel<<<NGRAPH, 256, 0, stream>>>(h2, goff, Wm, bm, out);
}